// Round 5
// baseline (132.477 us; speedup 1.0000x reference)
//
#include <hip/hip_runtime.h>

#define HDIM   256
#define HHALF  128
#define NTYPE  100
#define RPB    4       // crystals (rows) per block
#define S      260     // LDS row stride in floats (256 + 4 pad)

__device__ __forceinline__ float silu_f(float x) {
    return x / (1.0f + __expf(-x));
}

#define LD4(p) (*(const float4*)(p))
#define FMA4(A, s, v) do { (A).x += (s)*(v).x; (A).y += (s)*(v).y; \
                           (A).z += (s)*(v).z; (A).w += (s)*(v).w; } while (0)

// 1 row x 4 cols per thread, K=256 fixed, register ping-pong weight prefetch
// (8 weight rows in flight). hrow reads are wave-uniform LDS broadcasts.
template<bool ACT>
__device__ __forceinline__ void gemm_1x4(
    const float* hrow, const float* __restrict__ W, const int ldw,
    const float* __restrict__ bias, const int j0, const float scale, float* dst)
{
    float4 acc = make_float4(0.f, 0.f, 0.f, 0.f);
    const float* wp = W + j0;

    float4 x0 = LD4(wp);           float4 x1 = LD4(wp + ldw);
    float4 x2 = LD4(wp + 2 * ldw); float4 x3 = LD4(wp + 3 * ldw);
    float4 x4 = LD4(wp + 4 * ldw); float4 x5 = LD4(wp + 5 * ldw);
    float4 x6 = LD4(wp + 6 * ldw); float4 x7 = LD4(wp + 7 * ldw);

#define C8U(b0,b1,b2,b3,b4,b5,b6,b7,kk) do { \
    float4 ha = LD4(hrow + (kk)); float4 hb = LD4(hrow + (kk) + 4); \
    FMA4(acc, ha.x, b0); FMA4(acc, ha.y, b1); \
    FMA4(acc, ha.z, b2); FMA4(acc, ha.w, b3); \
    FMA4(acc, hb.x, b4); FMA4(acc, hb.y, b5); \
    FMA4(acc, hb.z, b6); FMA4(acc, hb.w, b7); } while (0)

#pragma unroll 1
    for (int k = 0; k <= HDIM - 32; k += 16) {
        const float* wy = wp + (size_t)(k + 8) * ldw;
        float4 y0 = LD4(wy);           float4 y1 = LD4(wy + ldw);
        float4 y2 = LD4(wy + 2 * ldw); float4 y3 = LD4(wy + 3 * ldw);
        float4 y4 = LD4(wy + 4 * ldw); float4 y5 = LD4(wy + 5 * ldw);
        float4 y6 = LD4(wy + 6 * ldw); float4 y7 = LD4(wy + 7 * ldw);
        C8U(x0, x1, x2, x3, x4, x5, x6, x7, k);
        const float* wx = wp + (size_t)(k + 16) * ldw;
        x0 = LD4(wx);           x1 = LD4(wx + ldw);
        x2 = LD4(wx + 2 * ldw); x3 = LD4(wx + 3 * ldw);
        x4 = LD4(wx + 4 * ldw); x5 = LD4(wx + 5 * ldw);
        x6 = LD4(wx + 6 * ldw); x7 = LD4(wx + 7 * ldw);
        C8U(y0, y1, y2, y3, y4, y5, y6, y7, k + 8);
    }
    {   // epilogue: rows 240..255
        const float* wy = wp + (size_t)(HDIM - 8) * ldw;
        float4 y0 = LD4(wy);           float4 y1 = LD4(wy + ldw);
        float4 y2 = LD4(wy + 2 * ldw); float4 y3 = LD4(wy + 3 * ldw);
        float4 y4 = LD4(wy + 4 * ldw); float4 y5 = LD4(wy + 5 * ldw);
        float4 y6 = LD4(wy + 6 * ldw); float4 y7 = LD4(wy + 7 * ldw);
        C8U(x0, x1, x2, x3, x4, x5, x6, x7, HDIM - 16);
        C8U(y0, y1, y2, y3, y4, y5, y6, y7, HDIM - 8);
    }
#undef C8U

    float4 b4 = LD4(bias + j0);
    float4 r;
    r.x = acc.x * scale + b4.x; r.y = acc.y * scale + b4.y;
    r.z = acc.z * scale + b4.z; r.w = acc.w * scale + b4.w;
    if (ACT) { r.x = silu_f(r.x); r.y = silu_f(r.y); r.z = silu_f(r.z); r.w = silu_f(r.w); }
    *(float4*)dst = r;
}

// One block = 4 crystals; computes everything AND streams per-atom outputs
// (atoms of a crystal are contiguous because batch is sorted).
__global__ __launch_bounds__(256, 4) void fused_kernel(
    const int* __restrict__ batch, int N,
    const float* __restrict__ t_emb,
    const float* __restrict__ w1a, const float* __restrict__ b1a,
    const float* __restrict__ w2a, const float* __restrict__ b2a,
    const float* __restrict__ wc1, const float* __restrict__ bc1,
    const float* __restrict__ wc2, const float* __restrict__ bc2,
    const float* __restrict__ wl1, const float* __restrict__ bl1,
    const float* __restrict__ wl2, const float* __restrict__ bl2,
    const float* __restrict__ wt,  const float* __restrict__ bt,
    float* __restrict__ out_coord,   // [N,3]
    float* __restrict__ cell_out,    // [B,6]
    float4* __restrict__ out_logits4)// [N,25] float4
{
    __shared__ float bufA[RPB * S];        // h0, then h
    __shared__ float bufB[RPB * S];        // h1, then gc(0..127)/gl(128..255)
    __shared__ float logits_s[RPB * 104];  // per-crystal logits rows
    __shared__ float coord_s[RPB * 4];     // per-crystal coord rows
    __shared__ int   lb_s[RPB + 1];
    __shared__ float cnt_s[RPB];

    const int tid = threadIdx.x;
    const int R0  = blockIdx.x * RPB;

    // atom ranges via binary search on sorted batch
    if (tid <= RPB) {
        int v = R0 + tid;
        int lo = 0, hi = N;
        while (lo < hi) { int mid = (lo + hi) >> 1; if (batch[mid] < v) lo = mid + 1; else hi = mid; }
        lb_s[tid] = lo;
    }

    // stage t_emb rows R0..R0+3 (each thread exactly one float4, coalesced)
    {
        const float4* src = (const float4*)(t_emb + (size_t)R0 * HDIM);
        int r = tid >> 6, kq = tid & 63;
        *(float4*)&bufA[r * S + kq * 4] = src[r * 64 + kq];
    }
    __syncthreads();
    if (tid < RPB) cnt_s[tid] = (float)(lb_s[tid + 1] - lb_s[tid]);

    const int cg = tid & 63;      // 64 col-groups x 4 cols = 256
    const int rg = tid >> 6;      // 4 rows
    const int j0 = cg * 4;

    // layer 1: h1 = silu(h0 @ w1a + b1a)   bufA -> bufB
    gemm_1x4<true>(&bufA[rg * S], w1a, HDIM, b1a, j0, 1.f, &bufB[rg * S + j0]);
    __syncthreads();

    // layer 2: h = h1 @ w2a + b2a          bufB -> bufA
    gemm_1x4<false>(&bufB[rg * S], w2a, HDIM, b2a, j0, 1.f, &bufA[rg * S + j0]);
    __syncthreads();

    // heads: coord hidden (tid<128) / cell hidden (tid>=128)   bufA -> bufB
    {
        const int t   = tid & 127;
        const int hcg = t & 31;        // 32 col-groups x 4 = 128 cols
        const int hrg = t >> 5;        // 4 rows
        const int hj0 = hcg * 4;
        const bool is_cell = (tid >= 128);
        const float* W  = is_cell ? wl1 : wc1;
        const float* bb = is_cell ? bl1 : bc1;
        // segment_sum == count * h; the scale commutes through the dot product
        const float sc = is_cell ? cnt_s[hrg] : 1.f;
        const int off  = is_cell ? HHALF : 0;
        gemm_1x4<true>(&bufA[hrg * S], W, HHALF, bb, hj0, sc,
                       &bufB[hrg * S + off + hj0]);
    }
    __syncthreads();

    // logits on waves 0-1 (tid<100); tiny heads on wave 2 (wave-level split,
    // no intra-wave serialization)
    if (tid < 100) {
        const int lr = tid / 25;          // row 0..3
        const int lq = tid - lr * 25;     // f4-col 0..24
        gemm_1x4<false>(&bufA[lr * S], wt, NTYPE, bt, lq * 4, 1.f,
                        &logits_s[lr * 104 + lq * 4]);
    } else if (tid >= 128 && tid < 128 + 36) {
        const int idx = tid - 128;
        if (idx < 12) {                   // coord: 4 rows x 3 cols, K=128
            int r = idx / 3, c = idx - 3 * r;
            float a = 0.f;
#pragma unroll 4
            for (int k = 0; k < HHALF; k += 4) {
                float4 hv = LD4(&bufB[r * S + k]);
                a += hv.x * wc2[(k + 0) * 3 + c] + hv.y * wc2[(k + 1) * 3 + c]
                   + hv.z * wc2[(k + 2) * 3 + c] + hv.w * wc2[(k + 3) * 3 + c];
            }
            coord_s[r * 4 + c] = a + bc2[c];
        } else {                          // cell: 4 rows x 6 cols, K=128
            int i2 = idx - 12;
            int r = i2 / 6, c = i2 - 6 * r;
            float a = 0.f;
#pragma unroll 4
            for (int k = 0; k < HHALF; k += 4) {
                float4 hv = LD4(&bufB[r * S + HHALF + k]);
                a += hv.x * wl2[(k + 0) * 6 + c] + hv.y * wl2[(k + 1) * 6 + c]
                   + hv.z * wl2[(k + 2) * 6 + c] + hv.w * wl2[(k + 3) * 6 + c];
            }
            cell_out[(size_t)(R0 + r) * 6 + c] = a + bl2[c];
        }
    }
    __syncthreads();

    // stream per-atom outputs: contiguous, coalesced float4 stores
    const float4* l4 = (const float4*)logits_s;
#pragma unroll 1
    for (int r = 0; r < RPB; ++r) {
        const int base = lb_s[r];
        const int cnt  = lb_s[r + 1] - base;
        const float4* lrow = l4 + r * 26;             // 104 floats = 26 f4
        const int tot = cnt * 25;
        for (int t = tid; t < tot; t += 256) {
            unsigned a = (unsigned)t / 25u;
            unsigned q = (unsigned)t - a * 25u;
            out_logits4[(size_t)(base + a) * 25 + q] = lrow[q];
        }
        const float c0 = coord_s[r * 4 + 0];
        const float c1 = coord_s[r * 4 + 1];
        const float c2 = coord_s[r * 4 + 2];
        const int tot3 = cnt * 3;
        float* oc = out_coord + (size_t)base * 3;
        for (int t = tid; t < tot3; t += 256) {
            unsigned a = (unsigned)t / 3u;
            unsigned c = (unsigned)t - a * 3u;
            oc[t] = (c == 0) ? c0 : (c == 1) ? c1 : c2;
        }
    }
}

extern "C" void kernel_launch(void* const* d_in, const int* in_sizes, int n_in,
                              void* d_out, int out_size, void* d_ws, size_t ws_size,
                              hipStream_t stream)
{
    const int*   batch = (const int*)d_in[1];
    const float* t_emb = (const float*)d_in[3];
    const float* w1a = (const float*)d_in[4];
    const float* b1a = (const float*)d_in[5];
    const float* w2a = (const float*)d_in[6];
    const float* b2a = (const float*)d_in[7];
    const float* wc1 = (const float*)d_in[8];
    const float* bc1 = (const float*)d_in[9];
    const float* wc2 = (const float*)d_in[10];
    const float* bc2 = (const float*)d_in[11];
    const float* wl1 = (const float*)d_in[12];
    const float* bl1 = (const float*)d_in[13];
    const float* wl2 = (const float*)d_in[14];
    const float* bl2 = (const float*)d_in[15];
    const float* wt  = (const float*)d_in[16];
    const float* bt  = (const float*)d_in[17];

    const int N = in_sizes[1];        // 500000
    const int B = in_sizes[2] / 9;    // 4096

    float* out        = (float*)d_out;
    float* out_coord  = out;                                   // [N,3]
    float* cell_out   = out + (size_t)N * 3;                   // [B,6]
    float* out_logits = out + (size_t)N * 3 + (size_t)B * 6;   // [N,100]

    fused_kernel<<<B / RPB, 256, 0, stream>>>(
        batch, N, t_emb,
        w1a, b1a, w2a, b2a,
        wc1, bc1, wc2, bc2,
        wl1, bl1, wl2, bl2,
        wt, bt,
        out_coord, cell_out, (float4*)out_logits);
}

// Round 7
// 109.805 us; speedup vs baseline: 1.2065x; 1.2065x over previous
//
#include <hip/hip_runtime.h>

#define HDIM   256
#define HHALF  128
#define NTYPE  100
#define RPB    8       // crystals (rows) per block
#define S      260     // LDS row stride in floats (256 + 4 pad)

typedef float f32x4_n __attribute__((ext_vector_type(4)));  // native vec for nontemporal

__device__ __forceinline__ float silu_f(float x) {
    return x / (1.0f + __expf(-x));
}

#define LD4(p) (*(const float4*)(p))
#define FMA4(A, s, v) do { (A).x += (s)*(v).x; (A).y += (s)*(v).y; \
                           (A).z += (s)*(v).z; (A).w += (s)*(v).w; } while (0)

// 2 rows x 4 cols per thread, K=256, weight prefetch DISTANCE 16 (two 8-row
// batches in flight; 3 live register sets via rotation). h reads are LDS
// wave-broadcasts. At consume time the batch was issued ~2 iterations ago
// (~290 device-cyc at 2 waves/SIMD) > ~200cyc L2 latency -> no stall.
template<bool ACT>
__device__ __forceinline__ void gemm_2x4(
    const float* hrow0, const float* hrow1,
    const float* __restrict__ W, const int ldw,
    const float* __restrict__ bias, const int j0,
    const float s0, const float s1,
    float* dst0, float* dst1)
{
    float4 acc0 = make_float4(0.f, 0.f, 0.f, 0.f);
    float4 acc1 = make_float4(0.f, 0.f, 0.f, 0.f);
    const float* wp = W + j0;

    float4 x0 = LD4(wp);           float4 x1 = LD4(wp + ldw);
    float4 x2 = LD4(wp + 2 * ldw); float4 x3 = LD4(wp + 3 * ldw);
    float4 x4 = LD4(wp + 4 * ldw); float4 x5 = LD4(wp + 5 * ldw);
    float4 x6 = LD4(wp + 6 * ldw); float4 x7 = LD4(wp + 7 * ldw);
    const float* wq = wp + (size_t)8 * ldw;
    float4 y0 = LD4(wq);           float4 y1 = LD4(wq + ldw);
    float4 y2 = LD4(wq + 2 * ldw); float4 y3 = LD4(wq + 3 * ldw);
    float4 y4 = LD4(wq + 4 * ldw); float4 y5 = LD4(wq + 5 * ldw);
    float4 y6 = LD4(wq + 6 * ldw); float4 y7 = LD4(wq + 7 * ldw);

#define C8(b0,b1,b2,b3,b4,b5,b6,b7,kk) do { \
    float4 ha = LD4(hrow0 + (kk)); float4 hb = LD4(hrow0 + (kk) + 4); \
    float4 ga = LD4(hrow1 + (kk)); float4 gb = LD4(hrow1 + (kk) + 4); \
    FMA4(acc0, ha.x, b0); FMA4(acc1, ga.x, b0); \
    FMA4(acc0, ha.y, b1); FMA4(acc1, ga.y, b1); \
    FMA4(acc0, ha.z, b2); FMA4(acc1, ga.z, b2); \
    FMA4(acc0, ha.w, b3); FMA4(acc1, ga.w, b3); \
    FMA4(acc0, hb.x, b4); FMA4(acc1, gb.x, b4); \
    FMA4(acc0, hb.y, b5); FMA4(acc1, gb.y, b5); \
    FMA4(acc0, hb.z, b6); FMA4(acc1, gb.z, b6); \
    FMA4(acc0, hb.w, b7); FMA4(acc1, gb.w, b7); } while (0)

#pragma unroll 1
    for (int k = 0; k <= HDIM - 32; k += 16) {
        // prefetch rows k+16..k+23, then consume X (rows k..k+7)
        const float* wz = wp + (size_t)(k + 16) * ldw;
        float4 z0 = LD4(wz);           float4 z1 = LD4(wz + ldw);
        float4 z2 = LD4(wz + 2 * ldw); float4 z3 = LD4(wz + 3 * ldw);
        float4 z4 = LD4(wz + 4 * ldw); float4 z5 = LD4(wz + 5 * ldw);
        float4 z6 = LD4(wz + 6 * ldw); float4 z7 = LD4(wz + 7 * ldw);
        C8(x0, x1, x2, x3, x4, x5, x6, x7, k);
        x0 = z0; x1 = z1; x2 = z2; x3 = z3; x4 = z4; x5 = z5; x6 = z6; x7 = z7;
        // prefetch rows k+24..k+31, then consume Y (rows k+8..k+15)
        const float* wv = wp + (size_t)(k + 24) * ldw;
        float4 v0 = LD4(wv);           float4 v1 = LD4(wv + ldw);
        float4 v2 = LD4(wv + 2 * ldw); float4 v3 = LD4(wv + 3 * ldw);
        float4 v4 = LD4(wv + 4 * ldw); float4 v5 = LD4(wv + 5 * ldw);
        float4 v6 = LD4(wv + 6 * ldw); float4 v7 = LD4(wv + 7 * ldw);
        C8(y0, y1, y2, y3, y4, y5, y6, y7, k + 8);
        y0 = v0; y1 = v1; y2 = v2; y3 = v3; y4 = v4; y5 = v5; y6 = v6; y7 = v7;
    }
    // epilogue: rows 240..255 already resident in X,Y
    C8(x0, x1, x2, x3, x4, x5, x6, x7, HDIM - 16);
    C8(y0, y1, y2, y3, y4, y5, y6, y7, HDIM - 8);
#undef C8

    float4 b4 = LD4(bias + j0);
    float4 r0, r1;
    r0.x = acc0.x * s0 + b4.x; r0.y = acc0.y * s0 + b4.y;
    r0.z = acc0.z * s0 + b4.z; r0.w = acc0.w * s0 + b4.w;
    r1.x = acc1.x * s1 + b4.x; r1.y = acc1.y * s1 + b4.y;
    r1.z = acc1.z * s1 + b4.z; r1.w = acc1.w * s1 + b4.w;
    if (ACT) {
        r0.x = silu_f(r0.x); r0.y = silu_f(r0.y); r0.z = silu_f(r0.z); r0.w = silu_f(r0.w);
        r1.x = silu_f(r1.x); r1.y = silu_f(r1.y); r1.z = silu_f(r1.z); r1.w = silu_f(r1.w);
    }
    *(float4*)dst0 = r0;
    *(float4*)dst1 = r1;
}

// One block = 8 crystals.
__global__ __launch_bounds__(256) void crystal_kernel(
    const int* __restrict__ batch, int N,
    const float* __restrict__ t_emb,
    const float* __restrict__ w1a, const float* __restrict__ b1a,
    const float* __restrict__ w2a, const float* __restrict__ b2a,
    const float* __restrict__ wc1, const float* __restrict__ bc1,
    const float* __restrict__ wc2, const float* __restrict__ bc2,
    const float* __restrict__ wl1, const float* __restrict__ bl1,
    const float* __restrict__ wl2, const float* __restrict__ bl2,
    const float* __restrict__ wt,  const float* __restrict__ bt,
    float* __restrict__ coord_b,   // [B,3]  ws
    float* __restrict__ logits_b,  // [B,100] ws
    float* __restrict__ cell_out)  // d_out + N*3, [B,6]
{
    __shared__ float bufA[RPB * S];   // h0, then h
    __shared__ float bufB[RPB * S];   // h1, then gc(cols 0..127)/gl(128..255)
    __shared__ int   lb_s[RPB + 1];
    __shared__ float cnt_s[RPB];

    const int tid = threadIdx.x;
    const int R0  = blockIdx.x * RPB;

    // per-crystal atom counts via binary search on sorted batch
    if (tid <= RPB) {
        int v = R0 + tid;
        int lo = 0, hi = N;
        while (lo < hi) { int mid = (lo + hi) >> 1; if (batch[mid] < v) lo = mid + 1; else hi = mid; }
        lb_s[tid] = lo;
    }

    // stage t_emb rows R0..R0+7 row-major (coalesced float4)
    {
        const float4* src = (const float4*)(t_emb + (size_t)R0 * HDIM);
        for (int i = tid; i < RPB * 64; i += 256) {
            int r = i >> 6, kq = i & 63;
            *(float4*)&bufA[r * S + kq * 4] = src[r * 64 + kq];
        }
    }
    __syncthreads();
    if (tid < RPB) cnt_s[tid] = (float)(lb_s[tid + 1] - lb_s[tid]);

    const int cg = tid & 63;      // 64 col-groups x 4 cols = 256
    const int rg = tid >> 6;      // 4 row-groups x 2 rows  = 8
    const int j0 = cg * 4;
    const int r0 = rg * 2;

    // layer 1: h1 = silu(h0 @ w1a + b1a)   bufA -> bufB
    gemm_2x4<true>(&bufA[r0 * S], &bufA[(r0 + 1) * S], w1a, HDIM, b1a, j0,
                   1.f, 1.f, &bufB[r0 * S + j0], &bufB[(r0 + 1) * S + j0]);
    __syncthreads();

    // layer 2: h = h1 @ w2a + b2a          bufB -> bufA
    gemm_2x4<false>(&bufB[r0 * S], &bufB[(r0 + 1) * S], w2a, HDIM, b2a, j0,
                    1.f, 1.f, &bufA[r0 * S + j0], &bufA[(r0 + 1) * S + j0]);
    __syncthreads();

    // heads: coord hidden (tid<128) / cell hidden (tid>=128)   bufA -> bufB
    {
        const int t   = tid & 127;
        const int hcg = t & 31;        // 32 col-groups x 4 = 128 cols
        const int hrg = t >> 5;        // 4 row-groups x 2 rows = 8
        const int hj0 = hcg * 4;
        const int hr0 = hrg * 2;
        const bool is_cell = (tid >= 128);
        const float* W  = is_cell ? wl1 : wc1;
        const float* bb = is_cell ? bl1 : bc1;
        // segment_sum == count * h; the scale commutes through the dot product
        const float sA = is_cell ? cnt_s[hr0]     : 1.f;
        const float sB = is_cell ? cnt_s[hr0 + 1] : 1.f;
        const int off  = is_cell ? HHALF : 0;
        gemm_2x4<true>(&bufA[hr0 * S], &bufA[(hr0 + 1) * S], W, HHALF, bb, hj0,
                       sA, sB,
                       &bufB[hr0 * S + off + hj0], &bufB[(hr0 + 1) * S + off + hj0]);
    }
    __syncthreads();

    // logits (lanes lcg<25) + tiny head outputs (lanes lcg>=25)
    {
        const int lcg = tid & 31;
        const int lrg = tid >> 5;      // 8 rows
        if (lcg < 25) {
            const int lj0 = lcg * 4;
            const float* hr = &bufA[lrg * S];
            const float* wp = wt + lj0;
            float4 acc = make_float4(0.f, 0.f, 0.f, 0.f);

            float4 x0 = LD4(wp);             float4 x1 = LD4(wp + NTYPE);
            float4 x2 = LD4(wp + 2 * NTYPE); float4 x3 = LD4(wp + 3 * NTYPE);
            float4 x4 = LD4(wp + 4 * NTYPE); float4 x5 = LD4(wp + 5 * NTYPE);
            float4 x6 = LD4(wp + 6 * NTYPE); float4 x7 = LD4(wp + 7 * NTYPE);
            const float* wq = wp + (size_t)8 * NTYPE;
            float4 y0 = LD4(wq);             float4 y1 = LD4(wq + NTYPE);
            float4 y2 = LD4(wq + 2 * NTYPE); float4 y3 = LD4(wq + 3 * NTYPE);
            float4 y4 = LD4(wq + 4 * NTYPE); float4 y5 = LD4(wq + 5 * NTYPE);
            float4 y6 = LD4(wq + 6 * NTYPE); float4 y7 = LD4(wq + 7 * NTYPE);

#define C8L(b0,b1,b2,b3,b4,b5,b6,b7,kk) do { \
    float4 ha = LD4(hr + (kk)); float4 hb = LD4(hr + (kk) + 4); \
    FMA4(acc, ha.x, b0); FMA4(acc, ha.y, b1); \
    FMA4(acc, ha.z, b2); FMA4(acc, ha.w, b3); \
    FMA4(acc, hb.x, b4); FMA4(acc, hb.y, b5); \
    FMA4(acc, hb.z, b6); FMA4(acc, hb.w, b7); } while (0)

#pragma unroll 1
            for (int k = 0; k <= HDIM - 32; k += 16) {
                const float* wz = wp + (size_t)(k + 16) * NTYPE;
                float4 z0 = LD4(wz);             float4 z1 = LD4(wz + NTYPE);
                float4 z2 = LD4(wz + 2 * NTYPE); float4 z3 = LD4(wz + 3 * NTYPE);
                float4 z4 = LD4(wz + 4 * NTYPE); float4 z5 = LD4(wz + 5 * NTYPE);
                float4 z6 = LD4(wz + 6 * NTYPE); float4 z7 = LD4(wz + 7 * NTYPE);
                C8L(x0, x1, x2, x3, x4, x5, x6, x7, k);
                x0 = z0; x1 = z1; x2 = z2; x3 = z3; x4 = z4; x5 = z5; x6 = z6; x7 = z7;
                const float* wv = wp + (size_t)(k + 24) * NTYPE;
                float4 v0 = LD4(wv);             float4 v1 = LD4(wv + NTYPE);
                float4 v2 = LD4(wv + 2 * NTYPE); float4 v3 = LD4(wv + 3 * NTYPE);
                float4 v4 = LD4(wv + 4 * NTYPE); float4 v5 = LD4(wv + 5 * NTYPE);
                float4 v6 = LD4(wv + 6 * NTYPE); float4 v7 = LD4(wv + 7 * NTYPE);
                C8L(y0, y1, y2, y3, y4, y5, y6, y7, k + 8);
                y0 = v0; y1 = v1; y2 = v2; y3 = v3; y4 = v4; y5 = v5; y6 = v6; y7 = v7;
            }
            C8L(x0, x1, x2, x3, x4, x5, x6, x7, HDIM - 16);
            C8L(y0, y1, y2, y3, y4, y5, y6, y7, HDIM - 8);
#undef C8L
            float4 b4 = LD4(bt + lj0);
            *(float4*)&logits_b[(size_t)(R0 + lrg) * NTYPE + lj0] =
                make_float4(acc.x + b4.x, acc.y + b4.y, acc.z + b4.z, acc.w + b4.w);
        } else {
            // 56 idle lanes cover 24 coord + 48 cell outputs
            int idx = lrg * 7 + (lcg - 25);
            for (int t = idx; t < 24 + 48; t += 56) {
                if (t < 24) {
                    int r = t / 3, c = t - 3 * r;
                    float a = 0.f;
#pragma unroll 4
                    for (int k = 0; k < HHALF; k += 4) {
                        float4 hv = *(const float4*)&bufB[r * S + k];
                        a += hv.x * wc2[(k + 0) * 3 + c] + hv.y * wc2[(k + 1) * 3 + c]
                           + hv.z * wc2[(k + 2) * 3 + c] + hv.w * wc2[(k + 3) * 3 + c];
                    }
                    coord_b[(size_t)(R0 + r) * 3 + c] = a + bc2[c];
                } else {
                    int t2 = t - 24;
                    int r = t2 / 6, c = t2 - 6 * r;
                    float a = 0.f;
#pragma unroll 4
                    for (int k = 0; k < HHALF; k += 4) {
                        float4 hv = *(const float4*)&bufB[r * S + HHALF + k];
                        a += hv.x * wl2[(k + 0) * 6 + c] + hv.y * wl2[(k + 1) * 6 + c]
                           + hv.z * wl2[(k + 2) * 6 + c] + hv.w * wl2[(k + 3) * 6 + c];
                    }
                    cell_out[(size_t)(R0 + r) * 6 + c] = a + bl2[c];
                }
            }
        }
    }
}

// Gather per-crystal tables out to per-atom outputs. HBM-write-bound (~206 MB).
// Non-temporal stores: the data is never re-read on device.
__global__ __launch_bounds__(256) void scatter_kernel(
    const int* __restrict__ batch,
    const float*  __restrict__ coord_b,
    const f32x4_n* __restrict__ logits_b4,  // [B][25] float4
    float*  __restrict__ out_coord,         // [N*3]
    f32x4_n* __restrict__ out_logits4,      // [N*25] float4
    int N)
{
    const int stride = gridDim.x * blockDim.x;
    const int g0 = blockIdx.x * blockDim.x + threadIdx.x;

    const int tot_c = N * 3;
    for (int g = g0; g < tot_c; g += stride) {
        unsigned ug = (unsigned)g;
        unsigned i = ug / 3u;
        unsigned c = ug - i * 3u;
        __builtin_nontemporal_store(coord_b[3u * (unsigned)batch[i] + c], &out_coord[g]);
    }

    const int tot_l = N * 25;
    for (int g = g0; g < tot_l; g += stride) {
        unsigned ug = (unsigned)g;
        unsigned i = ug / 25u;
        unsigned q = ug - i * 25u;
        f32x4_n v = logits_b4[25u * (unsigned)batch[i] + q];
        __builtin_nontemporal_store(v, &out_logits4[g]);
    }
}

extern "C" void kernel_launch(void* const* d_in, const int* in_sizes, int n_in,
                              void* d_out, int out_size, void* d_ws, size_t ws_size,
                              hipStream_t stream)
{
    const int*   batch = (const int*)d_in[1];
    const float* t_emb = (const float*)d_in[3];
    const float* w1a = (const float*)d_in[4];
    const float* b1a = (const float*)d_in[5];
    const float* w2a = (const float*)d_in[6];
    const float* b2a = (const float*)d_in[7];
    const float* wc1 = (const float*)d_in[8];
    const float* bc1 = (const float*)d_in[9];
    const float* wc2 = (const float*)d_in[10];
    const float* bc2 = (const float*)d_in[11];
    const float* wl1 = (const float*)d_in[12];
    const float* bl1 = (const float*)d_in[13];
    const float* wl2 = (const float*)d_in[14];
    const float* bl2 = (const float*)d_in[15];
    const float* wt  = (const float*)d_in[16];
    const float* bt  = (const float*)d_in[17];

    const int N = in_sizes[1];        // 500000
    const int B = in_sizes[2] / 9;    // 4096

    float* out        = (float*)d_out;
    float* out_coord  = out;                                   // [N,3]
    float* cell_out   = out + (size_t)N * 3;                   // [B,6]
    float* out_logits = out + (size_t)N * 3 + (size_t)B * 6;   // [N,100]

    float* logits_b = (float*)d_ws;                            // B*100 floats
    float* coord_b  = logits_b + (size_t)B * NTYPE;            // B*3 floats

    crystal_kernel<<<B / RPB, 256, 0, stream>>>(
        batch, N, t_emb,
        w1a, b1a, w2a, b2a,
        wc1, bc1, wc2, bc2,
        wl1, bl1, wl2, bl2,
        wt, bt,
        coord_b, logits_b, cell_out);

    scatter_kernel<<<2048, 256, 0, stream>>>(
        batch, coord_b, (const f32x4_n*)logits_b,
        out_coord, (f32x4_n*)out_logits, N);
}